// Round 1
// baseline (606.379 us; speedup 1.0000x reference)
//
#include <hip/hip_runtime.h>

// Problem constants (match reference)
#define HH 256
#define WW 256
#define HWSZ (HH * WW)
#define BB 32
#define CC 18
#define NBLK 3

// ---------------------------------------------------------------------------
// Kernel 1: zero the whole output buffer (604 MB). Pure HBM-write-bound.
// float4 stores = 16 B/lane, the coalescing sweet spot. Grid-stride so the
// grid size stays modest (2048 blocks ~= 8 blocks/CU).
// ---------------------------------------------------------------------------
__global__ void zero_fill_f4(float4* __restrict__ out, int n4) {
    const int stride = gridDim.x * blockDim.x;
    const float4 z = make_float4(0.f, 0.f, 0.f, 0.f);
    for (int i = blockIdx.x * blockDim.x + threadIdx.x; i < n4; i += stride) {
        out[i] = z;
    }
}

// ---------------------------------------------------------------------------
// Kernel 2: scatter the one-hot points. One thread per (b, c) pair, writing
// 4 planes: gen_poses[0], gen_poses[1] (sample-0 coords, replicated over B),
// step_poses[0], step_poses[1] (per-sample interpolated coords).
// All writes land at distinct addresses (each (plane,b,c) owns its own
// 256x256 slice), so no atomics needed.
// ---------------------------------------------------------------------------
__global__ void scatter_points(const float* __restrict__ pose1,
                               const float* __restrict__ pose2,
                               float* __restrict__ out) {
    int idx = blockIdx.x * blockDim.x + threadIdx.x;
    if (idx >= BB * CC) return;
    const int b = idx / CC;
    const int c = idx % CC;

    // ---- gen_poses: coords come from SAMPLE 0 for every b (reference quirk)
    {
        const float xf = pose1[(size_t)c * 2 + 0];
        const float yf = pose1[(size_t)c * 2 + 1];
        const int x = (int)truncf(xf);   // trunc toward zero, matches int()/jnp.trunc
        const int y = (int)truncf(yf);
        if (x >= 0 && x <= 255 && y >= 0 && y <= 255) {
            // gen_poses[0][b][c][x][y]
            out[((size_t)(0 * BB + b) * CC + c) * HWSZ + (size_t)x * WW + y] = 1.0f;
        }
    }
    {
        const float xf = pose2[(size_t)c * 2 + 0];
        const float yf = pose2[(size_t)c * 2 + 1];
        const int x = (int)truncf(xf);
        const int y = (int)truncf(yf);
        if (x >= 0 && x <= 255 && y >= 0 && y <= 255) {
            // gen_poses[1][b][c][x][y]
            out[((size_t)(1 * BB + b) * CC + c) * HWSZ + (size_t)x * WW + y] = 1.0f;
        }
    }

    // ---- step_poses: per-sample coords
    const float p1x = pose1[(size_t)idx * 2 + 0];
    const float p1y = pose1[(size_t)idx * 2 + 1];
    const float p2x = pose2[(size_t)idx * 2 + 0];
    const float p2y = pose2[(size_t)idx * 2 + 1];
    // jnp.floor_divide on floats == floor(x / y), computed in f32
    const float sx = floorf((p2x - p1x) / (float)NBLK);
    const float sy = floorf((p2y - p1y) / (float)NBLK);

    float cx = p1x + sx;   // sequential accumulation, same IEEE ops as ref
    float cy = p1y + sy;
    const size_t step_base = (size_t)2 * BB * CC * HWSZ;   // after gen_poses
    #pragma unroll
    for (int k = 0; k < NBLK - 1; ++k) {
        const int x = (int)truncf(cx);
        const int y = (int)truncf(cy);
        if (x >= 0 && x <= 255 && y >= 0 && y <= 255) {
            // step_poses[k][b][c][x][y]
            out[step_base + ((size_t)(k * BB + b) * CC + c) * HWSZ + (size_t)x * WW + y] = 1.0f;
        }
        cx += sx;
        cy += sy;
    }
}

extern "C" void kernel_launch(void* const* d_in, const int* in_sizes, int n_in,
                              void* d_out, int out_size, void* d_ws, size_t ws_size,
                              hipStream_t stream) {
    const float* pose1 = (const float*)d_in[0];   // [32, 18, 2] f32
    const float* pose2 = (const float*)d_in[1];   // [32, 18, 2] f32
    float* out = (float*)d_out;                   // [2,32,18,256,256] + [2,32,18,256,256]

    // out_size = 150,994,944 floats, divisible by 4.
    const int n4 = out_size / 4;
    zero_fill_f4<<<2048, 256, 0, stream>>>((float4*)out, n4);

    const int npts = BB * CC;  // 576
    scatter_points<<<(npts + 255) / 256, 256, 0, stream>>>(pose1, pose2, out);
}

// Round 2
// 568.255 us; speedup vs baseline: 1.0671x; 1.0671x over previous
//
#include <hip/hip_runtime.h>

// Problem constants (match reference)
#define HH 256
#define WW 256
#define HWSZ (HH * WW)
#define BB 32
#define CC 18
#define NBLK 3

// ---------------------------------------------------------------------------
// Scatter the one-hot points. One thread per (b, c) pair, writing 4 planes:
// gen_poses[0], gen_poses[1] (sample-0 coords, replicated over B),
// step_poses[0], step_poses[1] (per-sample interpolated coords).
// All writes land at distinct addresses (each (plane,b,c) owns its own
// 256x256 slice), so no atomics needed. Runs after the async memset on the
// same stream (stream order guarantees the zeros land first).
// ---------------------------------------------------------------------------
__global__ void scatter_points(const float* __restrict__ pose1,
                               const float* __restrict__ pose2,
                               float* __restrict__ out) {
    int idx = blockIdx.x * blockDim.x + threadIdx.x;
    if (idx >= BB * CC) return;
    const int b = idx / CC;
    const int c = idx % CC;

    // ---- gen_poses: coords come from SAMPLE 0 for every b (reference quirk)
    {
        const float xf = pose1[(size_t)c * 2 + 0];
        const float yf = pose1[(size_t)c * 2 + 1];
        const int x = (int)truncf(xf);   // trunc toward zero, matches int()/jnp.trunc
        const int y = (int)truncf(yf);
        if (x >= 0 && x <= 255 && y >= 0 && y <= 255) {
            // gen_poses[0][b][c][x][y]
            out[((size_t)(0 * BB + b) * CC + c) * HWSZ + (size_t)x * WW + y] = 1.0f;
        }
    }
    {
        const float xf = pose2[(size_t)c * 2 + 0];
        const float yf = pose2[(size_t)c * 2 + 1];
        const int x = (int)truncf(xf);
        const int y = (int)truncf(yf);
        if (x >= 0 && x <= 255 && y >= 0 && y <= 255) {
            // gen_poses[1][b][c][x][y]
            out[((size_t)(1 * BB + b) * CC + c) * HWSZ + (size_t)x * WW + y] = 1.0f;
        }
    }

    // ---- step_poses: per-sample coords
    const float p1x = pose1[(size_t)idx * 2 + 0];
    const float p1y = pose1[(size_t)idx * 2 + 1];
    const float p2x = pose2[(size_t)idx * 2 + 0];
    const float p2y = pose2[(size_t)idx * 2 + 1];
    // jnp.floor_divide on floats == floor(x / y), computed in f32
    const float sx = floorf((p2x - p1x) / (float)NBLK);
    const float sy = floorf((p2y - p1y) / (float)NBLK);

    float cx = p1x + sx;   // sequential accumulation, same IEEE ops as ref
    float cy = p1y + sy;
    const size_t step_base = (size_t)2 * BB * CC * HWSZ;   // after gen_poses
    #pragma unroll
    for (int k = 0; k < NBLK - 1; ++k) {
        const int x = (int)truncf(cx);
        const int y = (int)truncf(cy);
        if (x >= 0 && x <= 255 && y >= 0 && y <= 255) {
            // step_poses[k][b][c][x][y]
            out[step_base + ((size_t)(k * BB + b) * CC + c) * HWSZ + (size_t)x * WW + y] = 1.0f;
        }
        cx += sx;
        cy += sy;
    }
}

extern "C" void kernel_launch(void* const* d_in, const int* in_sizes, int n_in,
                              void* d_out, int out_size, void* d_ws, size_t ws_size,
                              hipStream_t stream) {
    const float* pose1 = (const float*)d_in[0];   // [32, 18, 2] f32
    const float* pose2 = (const float*)d_in[1];   // [32, 18, 2] f32
    float* out = (float*)d_out;                   // [2,32,18,256,256] + [2,32,18,256,256]

    // Zero the whole 604 MB output via the rocclr fill path (6.26 TB/s
    // demonstrated by the harness's own poison fill). Graph-capture-safe:
    // async memset becomes a graph memset node.
    hipMemsetAsync(d_out, 0, (size_t)out_size * sizeof(float), stream);

    const int npts = BB * CC;  // 576
    scatter_points<<<(npts + 255) / 256, 256, 0, stream>>>(pose1, pose2, out);
}